// Round 12
// baseline (61.217 us; speedup 1.0000x reference)
//
#include <hip/hip_runtime.h>
#include <math.h>

#define NB 128
#define NR 36
#define NT 128
#define ND 1024
#define WST 64            // w row stride (f16), cols 36..63 = 0
#define CST 260           // cap LDS tile row stride (f32): 1040 B, 16B-aligned

// ---- workspace layout (bytes), total ~6.9 MB ----
#define W_OFF  0u         // w   f16 [128][128][64]   = 2,097,152
#define SC_OFF 2097152u   // sc  f16 [128][8][4][16][36] = 4,718,592
#define NI_OFF 6815744u   // ni  f32 [128][36] sumsq  = 18,432
#define NC_OFF 6834176u   // nc  f32 [128][128] sumsq = 65,536
#define NORMS_N 20992     // (18432+65536)/4

typedef float    f32x4 __attribute__((ext_vector_type(4)));
typedef _Float16 f16x8 __attribute__((ext_vector_type(8)));
typedef _Float16 f16x4 __attribute__((ext_vector_type(4)));

__device__ __forceinline__ f16x8 cvt8(const float4 a, const float4 b) {
    f16x8 h;
    h[0] = (_Float16)a.x; h[1] = (_Float16)a.y; h[2] = (_Float16)a.z; h[3] = (_Float16)a.w;
    h[4] = (_Float16)b.x; h[5] = (_Float16)b.y; h[6] = (_Float16)b.z; h[7] = (_Float16)b.w;
    return h;
}
__device__ __forceinline__ f16x8 cvt8v(const f32x4 a, const f32x4 b) {
    f16x8 h;
    h[0] = (_Float16)a[0]; h[1] = (_Float16)a[1]; h[2] = (_Float16)a[2]; h[3] = (_Float16)a[3];
    h[4] = (_Float16)b[0]; h[5] = (_Float16)b[1]; h[6] = (_Float16)b[2]; h[7] = (_Float16)b[3];
    return h;
}
__device__ __forceinline__ float sq8(const float4 a, const float4 b, float s) {
    s = fmaf(a.x,a.x, fmaf(a.y,a.y, fmaf(a.z,a.z, fmaf(a.w,a.w, s))));
    return fmaf(b.x,b.x, fmaf(b.y,b.y, fmaf(b.z,b.z, fmaf(b.w,b.w, s))));
}
__device__ __forceinline__ float sq8v(const f32x4 a, const f32x4 b, float s) {
    s = fmaf(a[0],a[0], fmaf(a[1],a[1], fmaf(a[2],a[2], fmaf(a[3],a[3], s))));
    return fmaf(b[0],b[0], fmaf(b[1],b[1], fmaf(b[2],b[2], fmaf(b[3],b[3], s))));
}
// async global->LDS DMA: 16 B/lane; dest = uniform base + lane*16; source per-lane
__device__ __forceinline__ void gload_lds16(const void* g, float* l) {
    __builtin_amdgcn_global_load_lds(
        (const __attribute__((address_space(1))) void*)g,
        (__attribute__((address_space(3))) void*)l, 16, 0, 0);
}

// ============ K0: zero the norm accumulators ============
__global__ __launch_bounds__(256)
void zero_norms(float* p) {
    const int i = blockIdx.x * 256 + threadIdx.x;
    if (i < NORMS_N) p[i] = 0.f;
}

// ============ A1: partial dots, one wave per (b, 16-token group, K-quarter) ============
// No barriers. cap strip DMA'd coalesced into LDS (16 KB in flight/wave);
// img frags read from global (L2-hot, shared x8 tg on same XCD). Partials -> ws.
__global__ __launch_bounds__(64)
void dots(const float* __restrict__ img, const float* __restrict__ cap,
          char* __restrict__ ws) {
    __shared__ __align__(16) float capt[16 * CST];   // 16.6 KB

    const int lane = threadIdx.x;
    const int phys = blockIdx.x;
    // XCD swizzle: all 32 blocks of batch b on one XCD (matches B's mapping)
    const int lb = (phys & 7) * 512 + (phys >> 3);
    const int b  = lb >> 5;
    const int tg = (lb & 31) >> 2;
    const int kq = lb & 3;
    const int t0 = tg * 16;
    const int kb = kq * 256;

    const float* imgB = img + (size_t)b * NR * ND;

    // ---- 16 coalesced DMAs: cap rows t0..t0+15, K window [kb, kb+256) ----
    #pragma unroll
    for (int r = 0; r < 16; ++r) {
        const char* src = (const char*)(cap + ((size_t)(b * NT + t0 + r)) * ND + kb)
                          + lane * 16;
        gload_lds16(src, &capt[r * CST]);
    }
    asm volatile("s_waitcnt vmcnt(0)" ::: "memory");

    const int ln = lane & 15, hi = lane >> 4;

    const float* cRow  = capt + ln * CST + hi * 8;
    const float* imgR0 = imgB + (size_t)ln * ND + kb + hi * 8;
    const float* imgR1 = imgB + (size_t)(16 + ln) * ND + kb + hi * 8;
    const float* imgR2 = imgB + (size_t)(32 + (ln < 4 ? ln : 3)) * ND + kb + hi * 8;

    f32x4 acc0 = {0.f,0.f,0.f,0.f}, acc1 = acc0, acc2 = acc0;
    float ncp = 0.f, ni0 = 0.f, ni1 = 0.f, ni2 = 0.f;

    #pragma unroll
    for (int s = 0; s < 8; ++s) {
        const f32x4 ca = *(const f32x4*)(cRow + s * 32);
        const f32x4 cb = *(const f32x4*)(cRow + s * 32 + 4);
        const float4 g00 = *(const float4*)(imgR0 + s * 32);
        const float4 g01 = *(const float4*)(imgR0 + s * 32 + 4);
        const float4 g10 = *(const float4*)(imgR1 + s * 32);
        const float4 g11 = *(const float4*)(imgR1 + s * 32 + 4);
        const float4 g20 = *(const float4*)(imgR2 + s * 32);
        const float4 g21 = *(const float4*)(imgR2 + s * 32 + 4);
        ncp = sq8v(ca, cb, ncp);
        ni0 = sq8(g00, g01, ni0);
        ni1 = sq8(g10, g11, ni1);
        ni2 = sq8(g20, g21, ni2);
        const f16x8 a = cvt8v(ca, cb);
        acc0 = __builtin_amdgcn_mfma_f32_16x16x32_f16(a, cvt8(g00, g01), acc0, 0, 0, 0);
        acc1 = __builtin_amdgcn_mfma_f32_16x16x32_f16(a, cvt8(g10, g11), acc1, 0, 0, 0);
        acc2 = __builtin_amdgcn_mfma_f32_16x16x32_f16(a, cvt8(g20, g21), acc2, 0, 0, 0);
    }

    // ---- partial scores -> ws (f16, no atomics): C/D col=ln(region), row=hi*4+j(token) ----
    _Float16* scB = (_Float16*)(ws + SC_OFF)
                    + (size_t)(((b * 8 + tg) * 4 + kq) * 16) * 36;
    #pragma unroll
    for (int j = 0; j < 4; ++j) {
        _Float16* p = scB + (hi * 4 + j) * 36;
        p[ln]      = (_Float16)acc0[j];
        p[16 + ln] = (_Float16)acc1[j];
        if (ln < 4) p[32 + ln] = (_Float16)acc2[j];
    }

    // ---- norm sumsq partials -> global atomics (zeroed by K0) ----
    float* niW = (float*)(ws + NI_OFF) + b * NR;
    float* ncW = (float*)(ws + NC_OFF) + b * NT;
    {
        float s = ncp;  s += __shfl_xor(s, 16, 64); s += __shfl_xor(s, 32, 64);
        if (lane < 16) atomicAdd(&ncW[t0 + ln], s);
    }
    if (tg == 0) {   // img covered once per kq by tg==0 blocks
        float s = ni0; s += __shfl_xor(s, 16, 64); s += __shfl_xor(s, 32, 64);
        if (lane < 16) atomicAdd(&niW[ln], s);
        s = ni1;       s += __shfl_xor(s, 16, 64); s += __shfl_xor(s, 32, 64);
        if (lane < 16) atomicAdd(&niW[16 + ln], s);
        s = ni2;       s += __shfl_xor(s, 16, 64); s += __shfl_xor(s, 32, 64);
        if (lane < 4)  atomicAdd(&niW[32 + ln], s);
    }
}

// ============ A2: sum partials, softmax over regions, write w (f16) ============
__global__ __launch_bounds__(64)
void softmax_w(char* __restrict__ ws) {
    const int b = blockIdx.x >> 1;
    const int t = (blockIdx.x & 1) * 64 + threadIdx.x;   // 0..127

    const _Float16* sc = (const _Float16*)(ws + SC_OFF);
    const float* niW = (const float*)(ws + NI_OFF) + b * NR;
    const float* ncW = (const float*)(ws + NC_OFF) + b * NT;

    float v[NR];
    #pragma unroll
    for (int r = 0; r < NR; ++r) v[r] = 0.f;
    #pragma unroll
    for (int kq = 0; kq < 4; ++kq) {
        const _Float16* p = sc + (size_t)(((b * 8 + (t >> 4)) * 4 + kq) * 16 + (t & 15)) * 36;
        #pragma unroll
        for (int q = 0; q < 9; ++q) {
            const f16x4 h = *(const f16x4*)(p + q * 4);
            v[q*4]   += (float)h[0]; v[q*4+1] += (float)h[1];
            v[q*4+2] += (float)h[2]; v[q*4+3] += (float)h[3];
        }
    }

    const float nct = sqrtf(ncW[t]);
    float m = -1e30f;
    #pragma unroll
    for (int r = 0; r < NR; ++r) {
        const float d = fmaxf(sqrtf(niW[r]) * nct, 1e-8f);
        v[r] /= d;
        m = fmaxf(m, v[r]);
    }
    float sum = 0.f;
    #pragma unroll
    for (int r = 0; r < NR; ++r) { v[r] = __expf(v[r] - m); sum += v[r]; }
    const float inv = 1.f / sum;

    _Float16* wO = (_Float16*)(ws + W_OFF) + (size_t)(b * NT + t) * WST;
    #pragma unroll
    for (int q = 0; q < 8; ++q) {
        f16x8 h;
        #pragma unroll
        for (int j = 0; j < 8; ++j) {
            const int r = q * 8 + j;
            h[j] = (r < NR) ? (_Float16)(v[r] * inv) : (_Float16)0.f;
        }
        *(f16x8*)(wO + q * 8) = h;
    }
}

// ============ B: out[t][d] = sum_r w[t][r] * img[r][d] via MFMA (proven) ============
__global__ __launch_bounds__(256, 4)
void pool_mfma(const float* __restrict__ img, const _Float16* __restrict__ w_ws,
               float* __restrict__ out) {
    const int tid  = threadIdx.x;
    const int phys = blockIdx.x;
    const int lb = (phys & 7) * 256 + (phys >> 3);   // same XCD->batch mapping as A1
    const int b  = lb >> 4;
    const int tq = (lb >> 2) & 3;
    const int dq = lb & 3;
    const int t0 = tq * 32;

    const int wv = tid >> 6, lane = tid & 63, ln = lane & 15, hi = lane >> 4;
    const int dw = dq * 256 + wv * 64;

    const float*    imgB = img  + (size_t)b * NR * ND;
    const _Float16* wB   = w_ws + (size_t)(b * NT + t0) * WST;
    float*          outB = out  + ((size_t)(b * NT + t0)) * ND;

    f16x8 afr[2][2];
    #pragma unroll
    for (int mfr = 0; mfr < 2; ++mfr)
        #pragma unroll
        for (int kk = 0; kk < 2; ++kk)
            afr[mfr][kk] = *(const f16x8*)(wB + (mfr * 16 + ln) * WST + kk * 32 + hi * 8);

    f32x4 acc[2][4];
    #pragma unroll
    for (int mfr = 0; mfr < 2; ++mfr)
        #pragma unroll
        for (int nf = 0; nf < 4; ++nf)
            acc[mfr][nf] = (f32x4){0.f, 0.f, 0.f, 0.f};

    #pragma unroll
    for (int nf = 0; nf < 4; ++nf) {
        const int dcol = dw + nf * 16 + ln;
        #pragma unroll
        for (int kk = 0; kk < 2; ++kk) {
            f16x8 bfr;
            #pragma unroll
            for (int j = 0; j < 8; ++j) {
                int r = kk * 32 + hi * 8 + j;
                if (r >= NR) r = NR - 1;             // safe addr; killed by w==0
                bfr[j] = (_Float16)imgB[r * ND + dcol];
            }
            #pragma unroll
            for (int mfr = 0; mfr < 2; ++mfr)
                acc[mfr][nf] = __builtin_amdgcn_mfma_f32_16x16x32_f16(afr[mfr][kk], bfr, acc[mfr][nf], 0, 0, 0);
        }
    }

    #pragma unroll
    for (int mfr = 0; mfr < 2; ++mfr)
        #pragma unroll
        for (int nf = 0; nf < 4; ++nf)
            #pragma unroll
            for (int j = 0; j < 4; ++j)
                outB[(size_t)(mfr * 16 + hi * 4 + j) * ND + dw + nf * 16 + ln] = acc[mfr][nf][j];
}

extern "C" void kernel_launch(void* const* d_in, const int* in_sizes, int n_in,
                              void* d_out, int out_size, void* d_ws, size_t ws_size,
                              hipStream_t stream) {
    const float* img = (const float*)d_in[0];   // [B, R, D]
    const float* cap = (const float*)d_in[1];   // [B, T, D]
    float* out = (float*)d_out;                 // [B, T, D]
    char*  ws  = (char*)d_ws;                   // ~6.9 MB used

    zero_norms<<<(NORMS_N + 255) / 256, 256, 0, stream>>>((float*)(ws + NI_OFF));
    dots<<<NB * 32, 64, 0, stream>>>(img, cap, ws);
    softmax_w<<<NB * 2, 64, 0, stream>>>(ws);
    pool_mfma<<<NB * 16, 256, 0, stream>>>(img, (const _Float16*)(ws + W_OFF), out);
}